// Round 12
// baseline (2935.639 us; speedup 1.0000x reference)
//
#include <hip/hip_runtime.h>
#include <hip/hip_bf16.h>
#include <hip/hip_fp16.h>

// Problem constants (from the reference)
constexpr int NU = 80000;    // users
constexpr int NI = 40000;    // items
constexpr int K  = 64;       // feature dim
constexpr int NL = 3;        // layers
constexpr int NN = NU + NI;  // 120000 nodes
constexpr int NE = 1000000;  // edges (undirected; each contributes both dirs)
constexpr float EPS   = 1e-12f;
constexpr float SLOPE = 0.01f;

// Bucketed adjacency: bucket = row >> 7 (128 rows/bucket)
constexpr int BSH  = 7;
constexpr int NB   = (NN + (1 << BSH) - 1) >> BSH;   // 938 buckets
constexpr int CPAD = 32;   // counter stride in ints = 128 B -> one line per counter

// broadcast lane l's value to all lanes via v_readlane -> SGPR operand
__device__ __forceinline__ float bcast(float v, int l) {
    return __uint_as_float(__builtin_amdgcn_readlane(__float_as_uint(v), l));
}

// ---------------------------------------------------------------------------
// e0 = l2norm(concat(Gu, Gi)) stored fp16; gsum[n] = rowsum(e0)
// ---------------------------------------------------------------------------
__global__ __launch_bounds__(256)
void norm_init_kernel(const float* __restrict__ Gu, const float* __restrict__ Gi,
                      __half* __restrict__ e, float* __restrict__ gsum) {
    int node = blockIdx.x * 4 + (threadIdx.x >> 6);
    int lane = threadIdx.x & 63;
    if (node >= NN) return;
    float v = (node < NU) ? Gu[node * K + lane] : Gi[(node - NU) * K + lane];
    float ss = v * v;
    #pragma unroll
    for (int off = 32; off > 0; off >>= 1) ss += __shfl_xor(ss, off);
    float r = v / fmaxf(sqrtf(ss), EPS);
    e[(size_t)node * K + lane] = __float2half(r);
    float rs = r;
    #pragma unroll
    for (int off = 32; off > 0; off >>= 1) rs += __shfl_xor(rs, off);
    if (lane == 0) gsum[node] = rs;   // overwrite poison
}

// ---------------------------------------------------------------------------
// Bucket histogram: one PADDED counter per bucket (128 B apart -> no line
// contention; the R11 regression was 16 counters/line serializing on ~59 lines)
// ---------------------------------------------------------------------------
__global__ __launch_bounds__(256)
void bhist_kernel(const int* __restrict__ eu, const int* __restrict__ ei,
                  int* __restrict__ bcnt) {
    int e = blockIdx.x * blockDim.x + threadIdx.x;
    if (e >= NE) return;
    atomicAdd(&bcnt[(eu[e] >> BSH) * CPAD], 1);
    atomicAdd(&bcnt[(ei[e] >> BSH) * CPAD], 1);
}

// single-block exclusive scan of the 938 bucket counts -> boff, bcur
__global__ __launch_bounds__(1024)
void bscan_kernel(const int* __restrict__ bcnt, int* __restrict__ boff,
                  int* __restrict__ bcur) {
    __shared__ int sh[1024];
    int tid = threadIdx.x;
    int v = (tid < NB) ? bcnt[tid * CPAD] : 0;
    sh[tid] = v;
    __syncthreads();
    #pragma unroll
    for (int off = 1; off < 1024; off <<= 1) {
        int t = (tid >= off) ? sh[tid - off] : 0;
        __syncthreads();
        sh[tid] += t;
        __syncthreads();
    }
    if (tid < NB) {
        int excl = sh[tid] - v;
        boff[tid] = excl;
        bcur[tid * CPAD] = excl;
    }
    if (tid == 1023) boff[NB] = sh[1023];   // = 2*NE
}

// Scatter entries bucket-compacted: staging[p] = (row&127)<<17 | col.
// Padded cursors -> atomics parallel across 938 independent lines.
__global__ __launch_bounds__(256)
void fill_p1_kernel(const int* __restrict__ eu, const int* __restrict__ ei,
                    int* __restrict__ bcur, unsigned* __restrict__ staging) {
    int e = blockIdx.x * blockDim.x + threadIdx.x;
    if (e >= NE) return;
    int u = eu[e];
    int i = ei[e];
    int pu = atomicAdd(&bcur[(u >> BSH) * CPAD], 1);
    staging[pu] = ((unsigned)(u & 127) << 17) | (unsigned)i;
    int pi = atomicAdd(&bcur[(i >> BSH) * CPAD], 1);
    staging[pi] = ((unsigned)(i & 127) << 17) | (unsigned)u;
}

// ---------------------------------------------------------------------------
// SpMM via bucket-LDS scatter: block b owns 128 rows of side in a 32 KB LDS
// f32 tile; streams its staging entries, half-wave (32 lanes, __half2) gathers
// x[col] (4-deep unroll = 32 rows in flight/block) and ds_add_f32-accumulates
// into LDS; writes side coalesced (float4). No cols CSR, no global atomics.
// ---------------------------------------------------------------------------
__global__ __launch_bounds__(256)
void spmm_scatter_kernel(const int* __restrict__ boff,
                         const unsigned* __restrict__ staging,
                         const __half* __restrict__ x,
                         float* __restrict__ side) {
    __shared__ float acc[(1 << BSH) * K];   // 32 KB
    const int b = blockIdx.x;
    const int rbase = b << BSH;
    const int nrows = (NN - rbase < (1 << BSH)) ? (NN - rbase) : (1 << BSH);

    float4* a4 = (float4*)acc;
    for (int t = threadIdx.x; t < (1 << BSH) * K / 4; t += 256)
        a4[t] = make_float4(0.f, 0.f, 0.f, 0.f);
    __syncthreads();

    const int s = boff[b];
    const int e = boff[b + 1];
    const __half2* xp = (const __half2*)x;
    const int hw  = threadIdx.x >> 5;   // half-wave 0..7
    const int sub = threadIdx.x & 31;   // feature-pair index

    int t = s + hw * 4;
    for (; t + 3 < e; t += 32) {
        unsigned p0 = staging[t], p1 = staging[t + 1];
        unsigned p2 = staging[t + 2], p3 = staging[t + 3];
        float2 v0 = __half22float2(xp[(size_t)(p0 & 0x1FFFFu) * 32 + sub]);
        float2 v1 = __half22float2(xp[(size_t)(p1 & 0x1FFFFu) * 32 + sub]);
        float2 v2 = __half22float2(xp[(size_t)(p2 & 0x1FFFFu) * 32 + sub]);
        float2 v3 = __half22float2(xp[(size_t)(p3 & 0x1FFFFu) * 32 + sub]);
        int r0 = (int)(p0 >> 17), r1 = (int)(p1 >> 17);
        int r2 = (int)(p2 >> 17), r3 = (int)(p3 >> 17);
        atomicAdd(&acc[r0 * K + 2 * sub],     v0.x);
        atomicAdd(&acc[r0 * K + 2 * sub + 1], v0.y);
        atomicAdd(&acc[r1 * K + 2 * sub],     v1.x);
        atomicAdd(&acc[r1 * K + 2 * sub + 1], v1.y);
        atomicAdd(&acc[r2 * K + 2 * sub],     v2.x);
        atomicAdd(&acc[r2 * K + 2 * sub + 1], v2.y);
        atomicAdd(&acc[r3 * K + 2 * sub],     v3.x);
        atomicAdd(&acc[r3 * K + 2 * sub + 1], v3.y);
    }
    int tend = (t + 4 < e) ? (t + 4) : e;
    for (; t < tend; ++t) {
        unsigned pk = staging[t];
        float2 v = __half22float2(xp[(size_t)(pk & 0x1FFFFu) * 32 + sub]);
        int r = (int)(pk >> 17);
        atomicAdd(&acc[r * K + 2 * sub],     v.x);
        atomicAdd(&acc[r * K + 2 * sub + 1], v.y);
    }
    __syncthreads();

    float4* s4 = (float4*)(side + (size_t)rbase * K);
    for (int t2 = threadIdx.x; t2 < nrows * K / 4; t2 += 256)
        s4[t2] = a4[t2];
}

// ---------------------------------------------------------------------------
// Dense layer, register-GEMV (fp16 x in, fp16 y out, f32 compute):
//   p = side + x ; q = side * x
//   h = p@W1 + b1 + q@W2 + b2 ; y = l2norm(leaky_relu(h)) ; gsum += rowsum(y)
// ---------------------------------------------------------------------------
__global__ __launch_bounds__(256)
void layer_kernel(const __half* __restrict__ x, const float* __restrict__ side,
                  const float* __restrict__ W1, const float* __restrict__ b1,
                  const float* __restrict__ W2, const float* __restrict__ b2,
                  __half* __restrict__ y, float* __restrict__ gsum) {
    const int wave = threadIdx.x >> 6;
    const int lane = threadIdx.x & 63;

    float w1c[K], w2c[K];
    #pragma unroll
    for (int j = 0; j < K; ++j) {
        w1c[j] = W1[j * K + lane];
        w2c[j] = W2[j * K + lane];
    }
    const float bias = b1[lane] + b2[lane];

    for (int node = blockIdx.x * 4 + wave; node < NN; node += gridDim.x * 4) {
        float xv = __half2float(x[(size_t)node * K + lane]);
        float sv = side[(size_t)node * K + lane];
        float p = sv + xv;
        float q = sv * xv;
        float acc0 = bias, acc1 = 0.f, acc2 = 0.f, acc3 = 0.f;
        #pragma unroll
        for (int j = 0; j < K; j += 4) {
            acc0 = fmaf(bcast(p, j + 0), w1c[j + 0], acc0);
            acc0 = fmaf(bcast(q, j + 0), w2c[j + 0], acc0);
            acc1 = fmaf(bcast(p, j + 1), w1c[j + 1], acc1);
            acc1 = fmaf(bcast(q, j + 1), w2c[j + 1], acc1);
            acc2 = fmaf(bcast(p, j + 2), w1c[j + 2], acc2);
            acc2 = fmaf(bcast(q, j + 2), w2c[j + 2], acc2);
            acc3 = fmaf(bcast(p, j + 3), w1c[j + 3], acc3);
            acc3 = fmaf(bcast(q, j + 3), w2c[j + 3], acc3);
        }
        float acc = (acc0 + acc1) + (acc2 + acc3);

        float h = (acc > 0.f) ? acc : SLOPE * acc;
        float ss = h * h;
        #pragma unroll
        for (int off = 32; off > 0; off >>= 1) ss += __shfl_xor(ss, off);
        float r = h / fmaxf(sqrtf(ss), EPS);
        y[(size_t)node * K + lane] = __float2half(r);
        float rs = r;
        #pragma unroll
        for (int off = 32; off > 0; off >>= 1) rs += __shfl_xor(rs, off);
        if (lane == 0) gsum[node] += rs;   // one wave per node: no race
    }
}

// ---------------------------------------------------------------------------
// out[n] = gsum[n] / ((L+1)*K) = gsum[n] / 256
// ---------------------------------------------------------------------------
__global__ __launch_bounds__(256)
void finalize_kernel(const float* __restrict__ gsum, float* __restrict__ out) {
    int n = blockIdx.x * blockDim.x + threadIdx.x;
    if (n < NN) out[n] = gsum[n] * (1.0f / ((NL + 1) * K));
}

extern "C" void kernel_launch(void* const* d_in, const int* in_sizes, int n_in,
                              void* d_out, int out_size, void* d_ws, size_t ws_size,
                              hipStream_t stream) {
    const float* Gu = (const float*)d_in[0];
    const float* Gi = (const float*)d_in[1];
    const float* W1 = (const float*)d_in[2];   // [NL][K][K]
    const float* b1 = (const float*)d_in[3];   // [NL][K]
    const float* W2 = (const float*)d_in[4];
    const float* b2 = (const float*)d_in[5];
    const int*  edge = (const int*)d_in[6];    // [2][NE]
    float* out = (float*)d_out;

    // Workspace: xbuf0(h) | xbuf1(h) | side(f32) | gsum | bcnt(pad) | boff |
    //            bcur(pad) | staging(u32)            (~70 MB)
    __half*   xbuf0   = (__half*)d_ws;
    __half*   xbuf1   = xbuf0 + (size_t)NN * K;
    float*    side    = (float*)(xbuf1 + (size_t)NN * K);
    float*    gsum    = side + (size_t)NN * K;
    int*      bcnt    = (int*)(gsum + NN);
    int*      boff    = bcnt + NB * CPAD;
    int*      bcur    = boff + (NB + 1);
    unsigned* staging = (unsigned*)(bcur + NB * CPAD);

    const int* eu = edge;
    const int* ei = edge + NE;

    // --- bucketed adjacency build (once per launch) ---
    hipMemsetAsync(bcnt, 0, (size_t)NB * CPAD * sizeof(int), stream);
    bhist_kernel<<<(NE + 255) / 256, 256, 0, stream>>>(eu, ei, bcnt);
    bscan_kernel<<<1, 1024, 0, stream>>>(bcnt, boff, bcur);
    fill_p1_kernel<<<(NE + 255) / 256, 256, 0, stream>>>(eu, ei, bcur, staging);

    // --- embeddings ---
    norm_init_kernel<<<(NN + 3) / 4, 256, 0, stream>>>(Gu, Gi, xbuf0, gsum);

    __half* cur = xbuf0;
    __half* nxt = xbuf1;
    for (int l = 0; l < NL; ++l) {
        spmm_scatter_kernel<<<NB, 256, 0, stream>>>(boff, staging, cur, side);
        layer_kernel<<<1024, 256, 0, stream>>>(cur, side,
                                               W1 + (size_t)l * K * K, b1 + (size_t)l * K,
                                               W2 + (size_t)l * K * K, b2 + (size_t)l * K,
                                               nxt, gsum);
        __half* t = cur; cur = nxt; nxt = t;
    }

    finalize_kernel<<<(NN + 255) / 256, 256, 0, stream>>>(gsum, out);
}

// Round 13
// 775.858 us; speedup vs baseline: 3.7837x; 3.7837x over previous
//
#include <hip/hip_runtime.h>
#include <hip/hip_bf16.h>
#include <hip/hip_fp16.h>

// Problem constants (from the reference)
constexpr int NU = 80000;    // users
constexpr int NI = 40000;    // items
constexpr int K  = 64;       // feature dim
constexpr int NL = 3;        // layers
constexpr int NN = NU + NI;  // 120000 nodes
constexpr int NE = 1000000;  // edges (undirected; each contributes both dirs)
constexpr float EPS   = 1e-12f;
constexpr float SLOPE = 0.01f;

constexpr int SCAN_B = 256;
constexpr int NBLK   = (NN + SCAN_B - 1) / SCAN_B;   // 469 scan blocks

// broadcast lane l's value to all lanes via v_readlane -> SGPR operand
__device__ __forceinline__ float bcast(float v, int l) {
    return __uint_as_float(__builtin_amdgcn_readlane(__float_as_uint(v), l));
}

// ---------------------------------------------------------------------------
// e0 = l2norm(concat(Gu, Gi)) stored fp16; gsum[n] = rowsum(e0)
// ---------------------------------------------------------------------------
__global__ __launch_bounds__(256)
void norm_init_kernel(const float* __restrict__ Gu, const float* __restrict__ Gi,
                      __half* __restrict__ e, float* __restrict__ gsum) {
    int node = blockIdx.x * 4 + (threadIdx.x >> 6);
    int lane = threadIdx.x & 63;
    if (node >= NN) return;
    float v = (node < NU) ? Gu[node * K + lane] : Gi[(node - NU) * K + lane];
    float ss = v * v;
    #pragma unroll
    for (int off = 32; off > 0; off >>= 1) ss += __shfl_xor(ss, off);
    float r = v / fmaxf(sqrtf(ss), EPS);
    e[(size_t)node * K + lane] = __float2half(r);
    float rs = r;
    #pragma unroll
    for (int off = 32; off > 0; off >>= 1) rs += __shfl_xor(rs, off);
    if (lane == 0) gsum[node] = rs;   // overwrite poison
}

// ---------------------------------------------------------------------------
// CSR build: histogram -> hierarchical exclusive scan -> direct ticket fill.
// (R12 lesson: direct fill's 2M atomics over 120K row cursors spread across
//  ~7.5K lines are NOT the bottleneck; its 128MB line-amplified writes cost
//  ~177us total, which beat every "smarter" scheme tried so far.)
// ---------------------------------------------------------------------------
__global__ __launch_bounds__(256)
void hist_kernel(const int* __restrict__ eu, const int* __restrict__ ei,
                 int* __restrict__ rowptr) {
    int e = blockIdx.x * blockDim.x + threadIdx.x;
    if (e >= NE) return;
    atomicAdd(&rowptr[1 + eu[e]], 1);
    atomicAdd(&rowptr[1 + ei[e]], 1);
}

__global__ __launch_bounds__(SCAN_B)
void scan1_kernel(int* __restrict__ cnt, int* __restrict__ bsum) {
    __shared__ int sh[SCAN_B];
    int i = blockIdx.x * SCAN_B + threadIdx.x;
    int v = (i < NN) ? cnt[i] : 0;
    sh[threadIdx.x] = v;
    __syncthreads();
    #pragma unroll
    for (int off = 1; off < SCAN_B; off <<= 1) {
        int t = (threadIdx.x >= off) ? sh[threadIdx.x - off] : 0;
        __syncthreads();
        sh[threadIdx.x] += t;
        __syncthreads();
    }
    if (i < NN) cnt[i] = sh[threadIdx.x];
    if (threadIdx.x == SCAN_B - 1) bsum[blockIdx.x] = sh[SCAN_B - 1];
}

__global__ __launch_bounds__(512)
void scan2_kernel(int* __restrict__ bsum) {
    __shared__ int sh[512];
    int v = (threadIdx.x < NBLK) ? bsum[threadIdx.x] : 0;
    sh[threadIdx.x] = v;
    __syncthreads();
    #pragma unroll
    for (int off = 1; off < 512; off <<= 1) {
        int t = (threadIdx.x >= off) ? sh[threadIdx.x - off] : 0;
        __syncthreads();
        sh[threadIdx.x] += t;
        __syncthreads();
    }
    if (threadIdx.x < NBLK) bsum[threadIdx.x] = sh[threadIdx.x] - v; // exclusive
}

__global__ __launch_bounds__(SCAN_B)
void scan3_kernel(int* __restrict__ rowptr, const int* __restrict__ bsum,
                  int* __restrict__ cursor) {
    int i = blockIdx.x * SCAN_B + threadIdx.x;   // index into cnt = rowptr+1
    if (i < NN) {
        int v = rowptr[1 + i] + bsum[blockIdx.x];
        rowptr[1 + i] = v;                        // rowptr[i+1] final
        if (i + 1 < NN) cursor[i + 1] = v;        // start of node i+1
    }
    if (i == 0) cursor[0] = 0;
}

__global__ __launch_bounds__(256)
void fill_kernel(const int* __restrict__ eu, const int* __restrict__ ei,
                 int* __restrict__ cursor, int* __restrict__ cols) {
    int e = blockIdx.x * blockDim.x + threadIdx.x;
    if (e >= NE) return;
    int u = eu[e];
    int i = ei[e];
    int p = atomicAdd(&cursor[u], 1);
    cols[p] = i;
    int q = atomicAdd(&cursor[i], 1);
    cols[q] = u;
}

// ---------------------------------------------------------------------------
// Gather SpMM, half-wave-per-node (R9 version): each lane loads __half2
// (2 features), 32 lanes cover a 128B fp16 row, each wave gathers TWO nodes
// with 4-deep unroll = 8 outstanding row-fetches/wave. Wide grid (15000
// blocks) of independent waves -- max memory-level parallelism (R12 lesson).
// ---------------------------------------------------------------------------
__global__ __launch_bounds__(256)
void gather_kernel(const int* __restrict__ rowptr, const int* __restrict__ cols,
                   const __half* __restrict__ x, float* __restrict__ side) {
    int node = blockIdx.x * 8 + (threadIdx.x >> 5);   // 8 half-waves/block
    int sub  = threadIdx.x & 31;                      // feature-pair index
    if (node >= NN) return;
    const __half2* xp = (const __half2*)x;            // row n = xp[n*32 ...]
    int s = rowptr[node];
    int e = rowptr[node + 1];
    float ax0 = 0.f, ay0 = 0.f, ax1 = 0.f, ay1 = 0.f;
    float ax2 = 0.f, ay2 = 0.f, ax3 = 0.f, ay3 = 0.f;
    int t = s;
    for (; t + 4 <= e; t += 4) {
        int n0 = cols[t];
        int n1 = cols[t + 1];
        int n2 = cols[t + 2];
        int n3 = cols[t + 3];
        float2 v0 = __half22float2(xp[(size_t)n0 * 32 + sub]);
        float2 v1 = __half22float2(xp[(size_t)n1 * 32 + sub]);
        float2 v2 = __half22float2(xp[(size_t)n2 * 32 + sub]);
        float2 v3 = __half22float2(xp[(size_t)n3 * 32 + sub]);
        ax0 += v0.x; ay0 += v0.y;
        ax1 += v1.x; ay1 += v1.y;
        ax2 += v2.x; ay2 += v2.y;
        ax3 += v3.x; ay3 += v3.y;
    }
    for (; t < e; ++t) {
        float2 v = __half22float2(xp[(size_t)cols[t] * 32 + sub]);
        ax0 += v.x; ay0 += v.y;
    }
    float2 r;
    r.x = (ax0 + ax1) + (ax2 + ax3);
    r.y = (ay0 + ay1) + (ay2 + ay3);
    ((float2*)side)[(size_t)node * 32 + sub] = r;
}

// ---------------------------------------------------------------------------
// Dense layer, register-GEMV (fp16 x in, fp16 y out, f32 compute):
//   p = side + x ; q = side * x
//   h = p@W1 + b1 + q@W2 + b2 ; y = l2norm(leaky_relu(h)) ; gsum += rowsum(y)
// ---------------------------------------------------------------------------
__global__ __launch_bounds__(256)
void layer_kernel(const __half* __restrict__ x, const float* __restrict__ side,
                  const float* __restrict__ W1, const float* __restrict__ b1,
                  const float* __restrict__ W2, const float* __restrict__ b2,
                  __half* __restrict__ y, float* __restrict__ gsum) {
    const int wave = threadIdx.x >> 6;
    const int lane = threadIdx.x & 63;

    float w1c[K], w2c[K];
    #pragma unroll
    for (int j = 0; j < K; ++j) {
        w1c[j] = W1[j * K + lane];
        w2c[j] = W2[j * K + lane];
    }
    const float bias = b1[lane] + b2[lane];

    for (int node = blockIdx.x * 4 + wave; node < NN; node += gridDim.x * 4) {
        float xv = __half2float(x[(size_t)node * K + lane]);
        float sv = side[(size_t)node * K + lane];
        float p = sv + xv;
        float q = sv * xv;
        float acc0 = bias, acc1 = 0.f, acc2 = 0.f, acc3 = 0.f;
        #pragma unroll
        for (int j = 0; j < K; j += 4) {
            acc0 = fmaf(bcast(p, j + 0), w1c[j + 0], acc0);
            acc0 = fmaf(bcast(q, j + 0), w2c[j + 0], acc0);
            acc1 = fmaf(bcast(p, j + 1), w1c[j + 1], acc1);
            acc1 = fmaf(bcast(q, j + 1), w2c[j + 1], acc1);
            acc2 = fmaf(bcast(p, j + 2), w1c[j + 2], acc2);
            acc2 = fmaf(bcast(q, j + 2), w2c[j + 2], acc2);
            acc3 = fmaf(bcast(p, j + 3), w1c[j + 3], acc3);
            acc3 = fmaf(bcast(q, j + 3), w2c[j + 3], acc3);
        }
        float acc = (acc0 + acc1) + (acc2 + acc3);

        float h = (acc > 0.f) ? acc : SLOPE * acc;
        float ss = h * h;
        #pragma unroll
        for (int off = 32; off > 0; off >>= 1) ss += __shfl_xor(ss, off);
        float r = h / fmaxf(sqrtf(ss), EPS);
        y[(size_t)node * K + lane] = __float2half(r);
        float rs = r;
        #pragma unroll
        for (int off = 32; off > 0; off >>= 1) rs += __shfl_xor(rs, off);
        if (lane == 0) gsum[node] += rs;   // one wave per node: no race
    }
}

// ---------------------------------------------------------------------------
// out[n] = gsum[n] / ((L+1)*K) = gsum[n] / 256
// ---------------------------------------------------------------------------
__global__ __launch_bounds__(256)
void finalize_kernel(const float* __restrict__ gsum, float* __restrict__ out) {
    int n = blockIdx.x * blockDim.x + threadIdx.x;
    if (n < NN) out[n] = gsum[n] * (1.0f / ((NL + 1) * K));
}

extern "C" void kernel_launch(void* const* d_in, const int* in_sizes, int n_in,
                              void* d_out, int out_size, void* d_ws, size_t ws_size,
                              hipStream_t stream) {
    const float* Gu = (const float*)d_in[0];
    const float* Gi = (const float*)d_in[1];
    const float* W1 = (const float*)d_in[2];   // [NL][K][K]
    const float* b1 = (const float*)d_in[3];   // [NL][K]
    const float* W2 = (const float*)d_in[4];
    const float* b2 = (const float*)d_in[5];
    const int*  edge = (const int*)d_in[6];    // [2][NE]
    float* out = (float*)d_out;

    // Workspace: xbuf0(h) | xbuf1(h) | side(f32) | gsum | rowptr | bsum |
    //            cursor | cols                      (~71 MB)
    __half* xbuf0  = (__half*)d_ws;
    __half* xbuf1  = xbuf0 + (size_t)NN * K;
    float*  side   = (float*)(xbuf1 + (size_t)NN * K);
    float*  gsum   = side + (size_t)NN * K;
    int*    rowptr = (int*)(gsum + NN);
    int*    bsum   = rowptr + (NN + 1);
    int*    cursor = bsum + 512;
    int*    cols   = cursor + NN;

    const int* eu = edge;
    const int* ei = edge + NE;

    // --- CSR build (once per launch) ---
    hipMemsetAsync(rowptr, 0, (size_t)(NN + 1) * sizeof(int), stream);
    hist_kernel <<<(NE + 255) / 256, 256, 0, stream>>>(eu, ei, rowptr);
    scan1_kernel<<<NBLK, SCAN_B, 0, stream>>>(rowptr + 1, bsum);
    scan2_kernel<<<1, 512, 0, stream>>>(bsum);
    scan3_kernel<<<NBLK, SCAN_B, 0, stream>>>(rowptr, bsum, cursor);
    fill_kernel <<<(NE + 255) / 256, 256, 0, stream>>>(eu, ei, cursor, cols);

    // --- embeddings ---
    norm_init_kernel<<<(NN + 3) / 4, 256, 0, stream>>>(Gu, Gi, xbuf0, gsum);

    __half* cur = xbuf0;
    __half* nxt = xbuf1;
    for (int l = 0; l < NL; ++l) {
        gather_kernel<<<(NN + 7) / 8, 256, 0, stream>>>(rowptr, cols, cur, side);
        layer_kernel<<<1024, 256, 0, stream>>>(cur, side,
                                               W1 + (size_t)l * K * K, b1 + (size_t)l * K,
                                               W2 + (size_t)l * K * K, b2 + (size_t)l * K,
                                               nxt, gsum);
        __half* t = cur; cur = nxt; nxt = t;
    }

    finalize_kernel<<<(NN + 255) / 256, 256, 0, stream>>>(gsum, out);
}

// Round 14
// 744.733 us; speedup vs baseline: 3.9419x; 1.0418x over previous
//
#include <hip/hip_runtime.h>
#include <hip/hip_bf16.h>
#include <hip/hip_fp16.h>

// Problem constants (from the reference)
constexpr int NU = 80000;    // users
constexpr int NI = 40000;    // items
constexpr int K  = 64;       // feature dim
constexpr int NL = 3;        // layers
constexpr int NN = NU + NI;  // 120000 nodes
constexpr int NE = 1000000;  // edges (undirected; each contributes both dirs)
constexpr float EPS   = 1e-12f;
constexpr float SLOPE = 0.01f;

constexpr int SCAN_B = 256;
constexpr int NBLK   = (NN + SCAN_B - 1) / SCAN_B;   // 469 scan blocks

// broadcast lane l's value to all lanes via v_readlane -> SGPR operand
__device__ __forceinline__ float bcast(float v, int l) {
    return __uint_as_float(__builtin_amdgcn_readlane(__float_as_uint(v), l));
}

// ---------------------------------------------------------------------------
// e0 = l2norm(concat(Gu, Gi)) stored fp16; gsum[n] = rowsum(e0)
// ---------------------------------------------------------------------------
__global__ __launch_bounds__(256)
void norm_init_kernel(const float* __restrict__ Gu, const float* __restrict__ Gi,
                      __half* __restrict__ e, float* __restrict__ gsum) {
    int node = blockIdx.x * 4 + (threadIdx.x >> 6);
    int lane = threadIdx.x & 63;
    if (node >= NN) return;
    float v = (node < NU) ? Gu[node * K + lane] : Gi[(node - NU) * K + lane];
    float ss = v * v;
    #pragma unroll
    for (int off = 32; off > 0; off >>= 1) ss += __shfl_xor(ss, off);
    float r = v / fmaxf(sqrtf(ss), EPS);
    e[(size_t)node * K + lane] = __float2half(r);
    float rs = r;
    #pragma unroll
    for (int off = 32; off > 0; off >>= 1) rs += __shfl_xor(rs, off);
    if (lane == 0) gsum[node] = rs;   // overwrite poison
}

// ---------------------------------------------------------------------------
// CSR build: histogram -> hierarchical exclusive scan -> direct ticket fill.
// (Direct fill's 170us beat every "smarter" scheme tried: bucketed 2-pass
//  [R11: cursor-line contention], LDS scatter [R12: killed MLP].)
// ---------------------------------------------------------------------------
__global__ __launch_bounds__(256)
void hist_kernel(const int* __restrict__ eu, const int* __restrict__ ei,
                 int* __restrict__ rowptr) {
    int e = blockIdx.x * blockDim.x + threadIdx.x;
    if (e >= NE) return;
    atomicAdd(&rowptr[1 + eu[e]], 1);
    atomicAdd(&rowptr[1 + ei[e]], 1);
}

__global__ __launch_bounds__(SCAN_B)
void scan1_kernel(int* __restrict__ cnt, int* __restrict__ bsum) {
    __shared__ int sh[SCAN_B];
    int i = blockIdx.x * SCAN_B + threadIdx.x;
    int v = (i < NN) ? cnt[i] : 0;
    sh[threadIdx.x] = v;
    __syncthreads();
    #pragma unroll
    for (int off = 1; off < SCAN_B; off <<= 1) {
        int t = (threadIdx.x >= off) ? sh[threadIdx.x - off] : 0;
        __syncthreads();
        sh[threadIdx.x] += t;
        __syncthreads();
    }
    if (i < NN) cnt[i] = sh[threadIdx.x];
    if (threadIdx.x == SCAN_B - 1) bsum[blockIdx.x] = sh[SCAN_B - 1];
}

__global__ __launch_bounds__(512)
void scan2_kernel(int* __restrict__ bsum) {
    __shared__ int sh[512];
    int v = (threadIdx.x < NBLK) ? bsum[threadIdx.x] : 0;
    sh[threadIdx.x] = v;
    __syncthreads();
    #pragma unroll
    for (int off = 1; off < 512; off <<= 1) {
        int t = (threadIdx.x >= off) ? sh[threadIdx.x - off] : 0;
        __syncthreads();
        sh[threadIdx.x] += t;
        __syncthreads();
    }
    if (threadIdx.x < NBLK) bsum[threadIdx.x] = sh[threadIdx.x] - v; // exclusive
}

__global__ __launch_bounds__(SCAN_B)
void scan3_kernel(int* __restrict__ rowptr, const int* __restrict__ bsum,
                  int* __restrict__ cursor) {
    int i = blockIdx.x * SCAN_B + threadIdx.x;   // index into cnt = rowptr+1
    if (i < NN) {
        int v = rowptr[1 + i] + bsum[blockIdx.x];
        rowptr[1 + i] = v;                        // rowptr[i+1] final
        if (i + 1 < NN) cursor[i + 1] = v;        // start of node i+1
    }
    if (i == 0) cursor[0] = 0;
}

__global__ __launch_bounds__(256)
void fill_kernel(const int* __restrict__ eu, const int* __restrict__ ei,
                 int* __restrict__ cursor, int* __restrict__ cols) {
    int e = blockIdx.x * blockDim.x + threadIdx.x;
    if (e >= NE) return;
    int u = eu[e];
    int i = ei[e];
    int p = atomicAdd(&cursor[u], 1);
    cols[p] = i;
    int q = atomicAdd(&cursor[i], 1);
    cols[q] = u;
}

// ---------------------------------------------------------------------------
// Gather SpMM, QUARTER-wave-per-node: 16 lanes x 8B (uint2 = 2x half2) cover
// a 128B fp16 row; each wave owns 4 nodes x 4-deep unroll = 16 outstanding
// row-fetches/wave (2x the R13 half-wave). Latency/MLP-bound regime per
// R9->R13 measurements (fp16-width null, half-wave +80us).
// ---------------------------------------------------------------------------
__global__ __launch_bounds__(256)
void gather_kernel(const int* __restrict__ rowptr, const int* __restrict__ cols,
                   const __half* __restrict__ x, float* __restrict__ side) {
    int node = blockIdx.x * 16 + (threadIdx.x >> 4);  // 16 quarter-waves/block
    int sub  = threadIdx.x & 15;                      // 8B-chunk index in row
    if (node >= NN) return;
    const uint2* xp = (const uint2*)x;                // row n = xp[n*16 + sub]
    int s = rowptr[node];
    int e = rowptr[node + 1];

    float acc[4][4];   // [unroll-slot][feature] -- all indexing compile-time
    #pragma unroll
    for (int a = 0; a < 4; ++a)
        #pragma unroll
        for (int f = 0; f < 4; ++f) acc[a][f] = 0.f;

    int t = s;
    for (; t + 4 <= e; t += 4) {
        #pragma unroll
        for (int a = 0; a < 4; ++a) {
            uint2 v = xp[(size_t)cols[t + a] * 16 + sub];
            __half2 h0 = *(const __half2*)&v.x;
            __half2 h1 = *(const __half2*)&v.y;
            float2 f0 = __half22float2(h0);
            float2 f1 = __half22float2(h1);
            acc[a][0] += f0.x; acc[a][1] += f0.y;
            acc[a][2] += f1.x; acc[a][3] += f1.y;
        }
    }
    for (; t < e; ++t) {
        uint2 v = xp[(size_t)cols[t] * 16 + sub];
        __half2 h0 = *(const __half2*)&v.x;
        __half2 h1 = *(const __half2*)&v.y;
        float2 f0 = __half22float2(h0);
        float2 f1 = __half22float2(h1);
        acc[0][0] += f0.x; acc[0][1] += f0.y;
        acc[0][2] += f1.x; acc[0][3] += f1.y;
    }

    float4 r;
    r.x = (acc[0][0] + acc[1][0]) + (acc[2][0] + acc[3][0]);
    r.y = (acc[0][1] + acc[1][1]) + (acc[2][1] + acc[3][1]);
    r.z = (acc[0][2] + acc[1][2]) + (acc[2][2] + acc[3][2]);
    r.w = (acc[0][3] + acc[1][3]) + (acc[2][3] + acc[3][3]);
    ((float4*)side)[(size_t)node * 16 + sub] = r;   // 16 lanes x 16B = 256B/row
}

// ---------------------------------------------------------------------------
// Dense layer, register-GEMV (fp16 x in, fp16 y out, f32 compute):
//   p = side + x ; q = side * x
//   h = p@W1 + b1 + q@W2 + b2 ; y = l2norm(leaky_relu(h)) ; gsum += rowsum(y)
// ---------------------------------------------------------------------------
__global__ __launch_bounds__(256)
void layer_kernel(const __half* __restrict__ x, const float* __restrict__ side,
                  const float* __restrict__ W1, const float* __restrict__ b1,
                  const float* __restrict__ W2, const float* __restrict__ b2,
                  __half* __restrict__ y, float* __restrict__ gsum) {
    const int wave = threadIdx.x >> 6;
    const int lane = threadIdx.x & 63;

    float w1c[K], w2c[K];
    #pragma unroll
    for (int j = 0; j < K; ++j) {
        w1c[j] = W1[j * K + lane];
        w2c[j] = W2[j * K + lane];
    }
    const float bias = b1[lane] + b2[lane];

    for (int node = blockIdx.x * 4 + wave; node < NN; node += gridDim.x * 4) {
        float xv = __half2float(x[(size_t)node * K + lane]);
        float sv = side[(size_t)node * K + lane];
        float p = sv + xv;
        float q = sv * xv;
        float acc0 = bias, acc1 = 0.f, acc2 = 0.f, acc3 = 0.f;
        #pragma unroll
        for (int j = 0; j < K; j += 4) {
            acc0 = fmaf(bcast(p, j + 0), w1c[j + 0], acc0);
            acc0 = fmaf(bcast(q, j + 0), w2c[j + 0], acc0);
            acc1 = fmaf(bcast(p, j + 1), w1c[j + 1], acc1);
            acc1 = fmaf(bcast(q, j + 1), w2c[j + 1], acc1);
            acc2 = fmaf(bcast(p, j + 2), w1c[j + 2], acc2);
            acc2 = fmaf(bcast(q, j + 2), w2c[j + 2], acc2);
            acc3 = fmaf(bcast(p, j + 3), w1c[j + 3], acc3);
            acc3 = fmaf(bcast(q, j + 3), w2c[j + 3], acc3);
        }
        float acc = (acc0 + acc1) + (acc2 + acc3);

        float h = (acc > 0.f) ? acc : SLOPE * acc;
        float ss = h * h;
        #pragma unroll
        for (int off = 32; off > 0; off >>= 1) ss += __shfl_xor(ss, off);
        float r = h / fmaxf(sqrtf(ss), EPS);
        y[(size_t)node * K + lane] = __float2half(r);
        float rs = r;
        #pragma unroll
        for (int off = 32; off > 0; off >>= 1) rs += __shfl_xor(rs, off);
        if (lane == 0) gsum[node] += rs;   // one wave per node: no race
    }
}

// ---------------------------------------------------------------------------
// out[n] = gsum[n] / ((L+1)*K) = gsum[n] / 256
// ---------------------------------------------------------------------------
__global__ __launch_bounds__(256)
void finalize_kernel(const float* __restrict__ gsum, float* __restrict__ out) {
    int n = blockIdx.x * blockDim.x + threadIdx.x;
    if (n < NN) out[n] = gsum[n] * (1.0f / ((NL + 1) * K));
}

extern "C" void kernel_launch(void* const* d_in, const int* in_sizes, int n_in,
                              void* d_out, int out_size, void* d_ws, size_t ws_size,
                              hipStream_t stream) {
    const float* Gu = (const float*)d_in[0];
    const float* Gi = (const float*)d_in[1];
    const float* W1 = (const float*)d_in[2];   // [NL][K][K]
    const float* b1 = (const float*)d_in[3];   // [NL][K]
    const float* W2 = (const float*)d_in[4];
    const float* b2 = (const float*)d_in[5];
    const int*  edge = (const int*)d_in[6];    // [2][NE]
    float* out = (float*)d_out;

    // Workspace: xbuf0(h) | xbuf1(h) | side(f32) | gsum | rowptr | bsum |
    //            cursor | cols                      (~71 MB)
    __half* xbuf0  = (__half*)d_ws;
    __half* xbuf1  = xbuf0 + (size_t)NN * K;
    float*  side   = (float*)(xbuf1 + (size_t)NN * K);
    float*  gsum   = side + (size_t)NN * K;
    int*    rowptr = (int*)(gsum + NN);
    int*    bsum   = rowptr + (NN + 1);
    int*    cursor = bsum + 512;
    int*    cols   = cursor + NN;

    const int* eu = edge;
    const int* ei = edge + NE;

    // --- CSR build (once per launch) ---
    hipMemsetAsync(rowptr, 0, (size_t)(NN + 1) * sizeof(int), stream);
    hist_kernel <<<(NE + 255) / 256, 256, 0, stream>>>(eu, ei, rowptr);
    scan1_kernel<<<NBLK, SCAN_B, 0, stream>>>(rowptr + 1, bsum);
    scan2_kernel<<<1, 512, 0, stream>>>(bsum);
    scan3_kernel<<<NBLK, SCAN_B, 0, stream>>>(rowptr, bsum, cursor);
    fill_kernel <<<(NE + 255) / 256, 256, 0, stream>>>(eu, ei, cursor, cols);

    // --- embeddings ---
    norm_init_kernel<<<(NN + 3) / 4, 256, 0, stream>>>(Gu, Gi, xbuf0, gsum);

    __half* cur = xbuf0;
    __half* nxt = xbuf1;
    for (int l = 0; l < NL; ++l) {
        gather_kernel<<<(NN + 15) / 16, 256, 0, stream>>>(rowptr, cols, cur, side);
        layer_kernel<<<1024, 256, 0, stream>>>(cur, side,
                                               W1 + (size_t)l * K * K, b1 + (size_t)l * K,
                                               W2 + (size_t)l * K * K, b2 + (size_t)l * K,
                                               nxt, gsum);
        __half* t = cur; cur = nxt; nxt = t;
    }

    finalize_kernel<<<(NN + 255) / 256, 256, 0, stream>>>(gsum, out);
}

// Round 17
// 532.255 us; speedup vs baseline: 5.5155x; 1.3992x over previous
//
#include <hip/hip_runtime.h>
#include <hip/hip_bf16.h>
#include <hip/hip_fp16.h>

// Problem constants (from the reference)
constexpr int NU = 80000;    // users
constexpr int NI = 40000;    // items
constexpr int K  = 64;       // feature dim
constexpr int NL = 3;        // layers
constexpr int NN = NU + NI;  // 120000 nodes
constexpr int NE = 1000000;  // edges (undirected; each contributes both dirs)
constexpr float EPS   = 1e-12f;
constexpr float SLOPE = 0.01f;

constexpr int SCAN_B = 256;
constexpr int NBLK   = (NN + SCAN_B - 1) / SCAN_B;   // 469 scan blocks

typedef _Float16 half8 __attribute__((ext_vector_type(8)));
typedef float    f32x4 __attribute__((ext_vector_type(4)));

// ---------------------------------------------------------------------------
// e0 = l2norm(concat(Gu, Gi)) stored fp16; gsum[n] = rowsum(e0)
// ---------------------------------------------------------------------------
__global__ __launch_bounds__(256)
void norm_init_kernel(const float* __restrict__ Gu, const float* __restrict__ Gi,
                      __half* __restrict__ e, float* __restrict__ gsum) {
    int node = blockIdx.x * 4 + (threadIdx.x >> 6);
    int lane = threadIdx.x & 63;
    if (node >= NN) return;
    float v = (node < NU) ? Gu[node * K + lane] : Gi[(node - NU) * K + lane];
    float ss = v * v;
    #pragma unroll
    for (int off = 32; off > 0; off >>= 1) ss += __shfl_xor(ss, off);
    float r = v / fmaxf(sqrtf(ss), EPS);
    e[(size_t)node * K + lane] = __float2half(r);
    float rs = r;
    #pragma unroll
    for (int off = 32; off > 0; off >>= 1) rs += __shfl_xor(rs, off);
    if (lane == 0) gsum[node] = rs;   // overwrite poison
}

// ---------------------------------------------------------------------------
// CSR build: histogram -> hierarchical exclusive scan -> direct ticket fill.
// ---------------------------------------------------------------------------
__global__ __launch_bounds__(256)
void hist_kernel(const int* __restrict__ eu, const int* __restrict__ ei,
                 int* __restrict__ rowptr) {
    int e = blockIdx.x * blockDim.x + threadIdx.x;
    if (e >= NE) return;
    atomicAdd(&rowptr[1 + eu[e]], 1);
    atomicAdd(&rowptr[1 + ei[e]], 1);
}

__global__ __launch_bounds__(SCAN_B)
void scan1_kernel(int* __restrict__ cnt, int* __restrict__ bsum) {
    __shared__ int sh[SCAN_B];
    int i = blockIdx.x * SCAN_B + threadIdx.x;
    int v = (i < NN) ? cnt[i] : 0;
    sh[threadIdx.x] = v;
    __syncthreads();
    #pragma unroll
    for (int off = 1; off < SCAN_B; off <<= 1) {
        int t = (threadIdx.x >= off) ? sh[threadIdx.x - off] : 0;
        __syncthreads();
        sh[threadIdx.x] += t;
        __syncthreads();
    }
    if (i < NN) cnt[i] = sh[threadIdx.x];
    if (threadIdx.x == SCAN_B - 1) bsum[blockIdx.x] = sh[SCAN_B - 1];
}

__global__ __launch_bounds__(512)
void scan2_kernel(int* __restrict__ bsum) {
    __shared__ int sh[512];
    int v = (threadIdx.x < NBLK) ? bsum[threadIdx.x] : 0;
    sh[threadIdx.x] = v;
    __syncthreads();
    #pragma unroll
    for (int off = 1; off < 512; off <<= 1) {
        int t = (threadIdx.x >= off) ? sh[threadIdx.x - off] : 0;
        __syncthreads();
        sh[threadIdx.x] += t;
        __syncthreads();
    }
    if (threadIdx.x < NBLK) bsum[threadIdx.x] = sh[threadIdx.x] - v; // exclusive
}

__global__ __launch_bounds__(SCAN_B)
void scan3_kernel(int* __restrict__ rowptr, const int* __restrict__ bsum,
                  int* __restrict__ cursor) {
    int i = blockIdx.x * SCAN_B + threadIdx.x;   // index into cnt = rowptr+1
    if (i < NN) {
        int v = rowptr[1 + i] + bsum[blockIdx.x];
        rowptr[1 + i] = v;                        // rowptr[i+1] final
        if (i + 1 < NN) cursor[i + 1] = v;        // start of node i+1
    }
    if (i == 0) cursor[0] = 0;
}

__global__ __launch_bounds__(256)
void fill_kernel(const int* __restrict__ eu, const int* __restrict__ ei,
                 int* __restrict__ cursor, int* __restrict__ cols) {
    int e = blockIdx.x * blockDim.x + threadIdx.x;
    if (e >= NE) return;
    int u = eu[e];
    int i = ei[e];
    int p = atomicAdd(&cursor[u], 1);
    cols[p] = i;
    int q = atomicAdd(&cursor[i], 1);
    cols[q] = u;
}

// ---------------------------------------------------------------------------
// Gather SpMM, quarter-wave-per-node (R14 proven): 16 lanes x 8B cover a
// 128B fp16 row; 4 nodes/wave x 4-deep unroll = 16 outstanding row-fetches.
// ---------------------------------------------------------------------------
__global__ __launch_bounds__(256)
void gather_kernel(const int* __restrict__ rowptr, const int* __restrict__ cols,
                   const __half* __restrict__ x, float* __restrict__ side) {
    int node = blockIdx.x * 16 + (threadIdx.x >> 4);  // 16 quarter-waves/block
    int sub  = threadIdx.x & 15;                      // 8B-chunk index in row
    if (node >= NN) return;
    const uint2* xp = (const uint2*)x;                // row n = xp[n*16 + sub]
    int s = rowptr[node];
    int e = rowptr[node + 1];

    float acc[4][4];   // [unroll-slot][feature] -- all indexing compile-time
    #pragma unroll
    for (int a = 0; a < 4; ++a)
        #pragma unroll
        for (int f = 0; f < 4; ++f) acc[a][f] = 0.f;

    int t = s;
    for (; t + 4 <= e; t += 4) {
        #pragma unroll
        for (int a = 0; a < 4; ++a) {
            uint2 v = xp[(size_t)cols[t + a] * 16 + sub];
            __half2 h0 = *(const __half2*)&v.x;
            __half2 h1 = *(const __half2*)&v.y;
            float2 f0 = __half22float2(h0);
            float2 f1 = __half22float2(h1);
            acc[a][0] += f0.x; acc[a][1] += f0.y;
            acc[a][2] += f1.x; acc[a][3] += f1.y;
        }
    }
    for (; t < e; ++t) {
        uint2 v = xp[(size_t)cols[t] * 16 + sub];
        __half2 h0 = *(const __half2*)&v.x;
        __half2 h1 = *(const __half2*)&v.y;
        float2 f0 = __half22float2(h0);
        float2 f1 = __half22float2(h1);
        acc[0][0] += f0.x; acc[0][1] += f0.y;
        acc[0][2] += f1.x; acc[0][3] += f1.y;
    }

    float4 r;
    r.x = (acc[0][0] + acc[1][0]) + (acc[2][0] + acc[3][0]);
    r.y = (acc[0][1] + acc[1][1]) + (acc[2][1] + acc[3][1]);
    r.z = (acc[0][2] + acc[1][2]) + (acc[2][2] + acc[3][2]);
    r.w = (acc[0][3] + acc[1][3]) + (acc[2][3] + acc[3][3]);
    ((float4*)side)[(size_t)node * 16 + sub] = r;
}

// ---------------------------------------------------------------------------
// Dense layer via MFMA: H = [P|Q] (NNx128 fp16) @ [W1;W2] (128x64 fp16),
// f32 accumulate. One wave per 16-node tile: 16x mfma_f32_16x16x32_f16
// (4 col-tiles x {P,Q} x 2 k-halves). Layouts: A lane&15=row, lane>>4=k-group
// (8 halves); B lane&15=col, lane>>4=k-group; C col=lane&15,
// row=(lane>>4)*4+reg [HW-verified, m89]. k-group errors cancel (same
// grouping for A and B -> sum over k permutation-invariant).
// Epilogue: +bias, leaky, l2norm via 16-lane shfl_xor reduce, y fp16, gsum.
// NN/16 = 7500 tiles exactly (no tail).
// ---------------------------------------------------------------------------
__global__ __launch_bounds__(256)
void layer_mfma_kernel(const __half* __restrict__ x, const float* __restrict__ side,
                       const float* __restrict__ W1, const float* __restrict__ b1,
                       const float* __restrict__ W2, const float* __restrict__ b2,
                       __half* __restrict__ y, float* __restrict__ gsum) {
    const int lane = threadIdx.x & 63;
    const int g = lane >> 4;        // k-group (loads), C row-group (epilogue)
    const int c = lane & 15;        // A-row for loads; output col j-low
    const int gwave = blockIdx.x * 4 + (threadIdx.x >> 6);

    // B fragments: Bf[mat][h][ct]; mat 0=W1(P), 1=W2(Q); h = k-half of 64
    half8 Bf[2][2][4];
    #pragma unroll
    for (int m = 0; m < 2; ++m) {
        const float* W = m ? W2 : W1;
        #pragma unroll
        for (int h = 0; h < 2; ++h) {
            const int kb = h * 32 + g * 8;
            #pragma unroll
            for (int ct = 0; ct < 4; ++ct) {
                half8 f;
                #pragma unroll
                for (int e = 0; e < 8; ++e)
                    f[e] = (_Float16)W[(kb + e) * K + ct * 16 + c];
                Bf[m][h][ct] = f;
            }
        }
    }
    float biasv[4];
    #pragma unroll
    for (int ct = 0; ct < 4; ++ct) biasv[ct] = b1[ct * 16 + c] + b2[ct * 16 + c];

    for (int t = gwave; t < NN / 16; t += gridDim.x * 4) {
        const int nbase = t * 16;
        f32x4 C[4];
        #pragma unroll
        for (int ct = 0; ct < 4; ++ct) C[ct] = (f32x4){0.f, 0.f, 0.f, 0.f};

        #pragma unroll
        for (int h = 0; h < 2; ++h) {
            // lane loads row (nbase+c), k = h*32 + g*8 .. +8  (32B side, 16B x)
            const float*  sp = side + (size_t)(nbase + c) * K + h * 32 + g * 8;
            const __half* xq = x    + (size_t)(nbase + c) * K + h * 32 + g * 8;
            float4 s0 = *(const float4*)sp;
            float4 s1 = *(const float4*)(sp + 4);
            uint4 xv = *(const uint4*)xq;
            const __half2* xh = (const __half2*)&xv;
            float xs[8];
            #pragma unroll
            for (int e2 = 0; e2 < 4; ++e2) {
                float2 f2 = __half22float2(xh[e2]);
                xs[e2 * 2] = f2.x; xs[e2 * 2 + 1] = f2.y;
            }
            const float sv[8] = {s0.x, s0.y, s0.z, s0.w, s1.x, s1.y, s1.z, s1.w};
            half8 ph, qh;
            #pragma unroll
            for (int e = 0; e < 8; ++e) {
                ph[e] = (_Float16)(sv[e] + xs[e]);
                qh[e] = (_Float16)(sv[e] * xs[e]);
            }
            #pragma unroll
            for (int ct = 0; ct < 4; ++ct) {
                C[ct] = __builtin_amdgcn_mfma_f32_16x16x32_f16(ph, Bf[0][h][ct], C[ct], 0, 0, 0);
                C[ct] = __builtin_amdgcn_mfma_f32_16x16x32_f16(qh, Bf[1][h][ct], C[ct], 0, 0, 0);
            }
        }

        // epilogue: bias + leaky + l2norm + y + gsum
        #pragma unroll
        for (int r = 0; r < 4; ++r) {
            float hv[4];
            float hsum = 0.f, hsq = 0.f;
            #pragma unroll
            for (int ct = 0; ct < 4; ++ct) {
                float v = C[ct][r] + biasv[ct];
                v = (v > 0.f) ? v : SLOPE * v;
                hv[ct] = v;
                hsum += v;
                hsq  += v * v;
            }
            #pragma unroll
            for (int off = 1; off < 16; off <<= 1) {
                hsum += __shfl_xor(hsum, off);
                hsq  += __shfl_xor(hsq,  off);
            }
            const float inv = 1.f / fmaxf(sqrtf(hsq), EPS);
            const int node = nbase + 4 * g + r;
            #pragma unroll
            for (int ct = 0; ct < 4; ++ct)
                y[(size_t)node * K + ct * 16 + c] = __float2half(hv[ct] * inv);
            if (c == 0) gsum[node] += hsum * inv;   // one wave owns the tile
        }
    }
}

// ---------------------------------------------------------------------------
// out[n] = gsum[n] / ((L+1)*K) = gsum[n] / 256
// ---------------------------------------------------------------------------
__global__ __launch_bounds__(256)
void finalize_kernel(const float* __restrict__ gsum, float* __restrict__ out) {
    int n = blockIdx.x * blockDim.x + threadIdx.x;
    if (n < NN) out[n] = gsum[n] * (1.0f / ((NL + 1) * K));
}

extern "C" void kernel_launch(void* const* d_in, const int* in_sizes, int n_in,
                              void* d_out, int out_size, void* d_ws, size_t ws_size,
                              hipStream_t stream) {
    const float* Gu = (const float*)d_in[0];
    const float* Gi = (const float*)d_in[1];
    const float* W1 = (const float*)d_in[2];   // [NL][K][K]
    const float* b1 = (const float*)d_in[3];   // [NL][K]
    const float* W2 = (const float*)d_in[4];
    const float* b2 = (const float*)d_in[5];
    const int*  edge = (const int*)d_in[6];    // [2][NE]
    float* out = (float*)d_out;

    // Workspace: xbuf0(h) | xbuf1(h) | side(f32) | gsum | rowptr | bsum |
    //            cursor | cols                      (~71 MB)
    __half* xbuf0  = (__half*)d_ws;
    __half* xbuf1  = xbuf0 + (size_t)NN * K;
    float*  side   = (float*)(xbuf1 + (size_t)NN * K);
    float*  gsum   = side + (size_t)NN * K;
    int*    rowptr = (int*)(gsum + NN);
    int*    bsum   = rowptr + (NN + 1);
    int*    cursor = bsum + 512;
    int*    cols   = cursor + NN;

    const int* eu = edge;
    const int* ei = edge + NE;

    // --- CSR build (once per launch) ---
    hipMemsetAsync(rowptr, 0, (size_t)(NN + 1) * sizeof(int), stream);
    hist_kernel <<<(NE + 255) / 256, 256, 0, stream>>>(eu, ei, rowptr);
    scan1_kernel<<<NBLK, SCAN_B, 0, stream>>>(rowptr + 1, bsum);
    scan2_kernel<<<1, 512, 0, stream>>>(bsum);
    scan3_kernel<<<NBLK, SCAN_B, 0, stream>>>(rowptr, bsum, cursor);
    fill_kernel <<<(NE + 255) / 256, 256, 0, stream>>>(eu, ei, cursor, cols);

    // --- embeddings ---
    norm_init_kernel<<<(NN + 3) / 4, 256, 0, stream>>>(Gu, Gi, xbuf0, gsum);

    __half* cur = xbuf0;
    __half* nxt = xbuf1;
    for (int l = 0; l < NL; ++l) {
        gather_kernel<<<(NN + 15) / 16, 256, 0, stream>>>(rowptr, cols, cur, side);
        layer_mfma_kernel<<<1024, 256, 0, stream>>>(cur, side,
                                                    W1 + (size_t)l * K * K, b1 + (size_t)l * K,
                                                    W2 + (size_t)l * K * K, b2 + (size_t)l * K,
                                                    nxt, gsum);
        __half* t = cur; cur = nxt; nxt = t;
    }

    finalize_kernel<<<(NN + 255) / 256, 256, 0, stream>>>(gsum, out);
}